// Round 1
// baseline (125.487 us; speedup 1.0000x reference)
//
#include <hip/hip_runtime.h>

// Problem: B=2, T=2048, C=1024, H=16, D=64
// qkv = x @ w + b ; q,k,v split; att = relu(causal(q k^T / 8)); y = att @ v
// Output fp32 [B,T,C]. Compute in bf16 MFMA with fp32 accum.

typedef unsigned int u32;
typedef unsigned short ushort_t;
typedef float  f32x4 __attribute__((ext_vector_type(4)));
typedef short  s16x8 __attribute__((ext_vector_type(8)));

#define MFMA_BF16(a, b, c) __builtin_amdgcn_mfma_f32_16x16x32_bf16((a), (b), (c), 0, 0, 0)

#define GLOAD16(g, l)                                                        \
  __builtin_amdgcn_global_load_lds(                                          \
      (__attribute__((address_space(1))) void*)(g),                          \
      (__attribute__((address_space(3))) void*)(l), 16, 0, 0)

__device__ __forceinline__ unsigned short f2bf(float f) {
  union { float f; u32 u; } x; x.f = f;
  u32 r = (x.u + 0x7fffu + ((x.u >> 16) & 1u)) >> 16;
  return (unsigned short)r;
}

// ---------------- kernel 1: x fp32 -> bf16 ----------------
__global__ void cvt_x_kernel(const float* __restrict__ x, unsigned short* __restrict__ xb) {
  int i = blockIdx.x * 256 + threadIdx.x;           // 4M elems / 4 = 1M threads
  float4 v = ((const float4*)x)[i];
  ushort4 o;
  o.x = f2bf(v.x); o.y = f2bf(v.y); o.z = f2bf(v.z); o.w = f2bf(v.w);
  ((ushort4*)xb)[i] = o;
}

// ---------------- kernel 2: w [1024][3072] fp32 -> wT [3072][1024] bf16 ----
__global__ void transpose_w_kernel(const float* __restrict__ w, unsigned short* __restrict__ wT) {
  __shared__ unsigned short TL[64][72];             // [c][r], +8 pad
  const int tid = threadIdx.x;
  const int c0 = blockIdx.x * 64;                   // N dim (3072)
  const int r0 = blockIdx.y * 64;                   // K dim (1024)
#pragma unroll
  for (int p = 0; p < 4; ++p) {
    int r = p * 16 + (tid >> 4);
    int c = (tid & 15) * 4;
    float4 v = *(const float4*)&w[(size_t)(r0 + r) * 3072 + c0 + c];
    TL[c + 0][r] = f2bf(v.x);
    TL[c + 1][r] = f2bf(v.y);
    TL[c + 2][r] = f2bf(v.z);
    TL[c + 3][r] = f2bf(v.w);
  }
  __syncthreads();
#pragma unroll
  for (int p = 0; p < 4; ++p) {
    int c = p * 16 + (tid >> 4);
    int r = (tid & 15) * 4;
    ushort4 o;
    o.x = TL[c][r + 0]; o.y = TL[c][r + 1]; o.z = TL[c][r + 2]; o.w = TL[c][r + 3];
    *(ushort4*)&wT[(size_t)(c0 + c) * 1024 + r0 + r] = o;
  }
}

// ---------------- kernel 3: GEMM qkv = xb @ wT^T + bias  (bf16 out) -------
// A [4096][1024] bf16, Bt [3072][1024] bf16, C [4096][3072] bf16
// 128x128 tile, BK=32, 256 thr / 4 waves (2x2), each wave 64x64 = 4x4 frags.
__global__ __launch_bounds__(256, 2) void gemm_qkv_kernel(
    const unsigned short* __restrict__ A, const unsigned short* __restrict__ Bt,
    const float* __restrict__ bias, unsigned short* __restrict__ Cq) {
  __shared__ __align__(16) unsigned short As[128 * 32];
  __shared__ __align__(16) unsigned short Bs[128 * 32];
  const int tid = threadIdx.x;
  const int lane = tid & 63, wid = tid >> 6;
  const int wr = wid >> 1, wc = wid & 1;
  const int g = lane >> 4, lm = lane & 15;
  const int bm = blockIdx.y, bn = blockIdx.x;

  // staging: wave w covers rows [w*32, w*32+32); each call = 16 rows (64 lanes x 16B)
  const unsigned short* gA = A  + (size_t)(bm * 128 + wid * 32 + (lane >> 2)) * 1024 + (lane & 3) * 8;
  const unsigned short* gB = Bt + (size_t)(bn * 128 + wid * 32 + (lane >> 2)) * 1024 + (lane & 3) * 8;
  unsigned short* lA0 = &As[wid * 1024];
  unsigned short* lA1 = &As[wid * 1024 + 512];
  unsigned short* lB0 = &Bs[wid * 1024];
  unsigned short* lB1 = &Bs[wid * 1024 + 512];

  f32x4 acc[4][4] = {};

  for (int kt = 0; kt < 32; ++kt) {
    __syncthreads();
    const unsigned short* a0 = gA + kt * 32;
    const unsigned short* b0 = gB + kt * 32;
    GLOAD16(a0,             lA0);
    GLOAD16(a0 + 16 * 1024, lA1);
    GLOAD16(b0,             lB0);
    GLOAD16(b0 + 16 * 1024, lB1);
    __syncthreads();

    s16x8 af[4], bf[4];
#pragma unroll
    for (int m = 0; m < 4; ++m)
      af[m] = *(const s16x8*)&As[(wr * 64 + m * 16 + lm) * 32 + g * 8];
#pragma unroll
    for (int n = 0; n < 4; ++n)
      bf[n] = *(const s16x8*)&Bs[(wc * 64 + n * 16 + lm) * 32 + g * 8];
#pragma unroll
    for (int m = 0; m < 4; ++m)
#pragma unroll
      for (int n = 0; n < 4; ++n)
        acc[m][n] = MFMA_BF16(af[m], bf[n], acc[m][n]);
  }

  // epilogue: C row = bm*128 + wr*64 + m*16 + g*4 + r ; col = bn*128 + wc*64 + n*16 + lm
#pragma unroll
  for (int m = 0; m < 4; ++m) {
    const int row = bm * 128 + wr * 64 + m * 16 + g * 4;
#pragma unroll
    for (int n = 0; n < 4; ++n) {
      const int col = bn * 128 + wc * 64 + n * 16 + lm;
      const float bv = bias[col];
#pragma unroll
      for (int r = 0; r < 4; ++r)
        Cq[(size_t)(row + r) * 3072 + col] = f2bf(acc[m][n][r] + bv);
    }
  }
}

// ---------------- kernel 4: V part of qkv -> Vt [B][H][D][T] bf16 ---------
__global__ void transpose_v_kernel(const unsigned short* __restrict__ qkv,
                                   unsigned short* __restrict__ Vt) {
  __shared__ unsigned short TL[64][72];             // [d][t], +8 pad
  const int tid = threadIdx.x;
  const int t0 = blockIdx.x * 64;
  const int h = blockIdx.y;
  const int b = blockIdx.z;
#pragma unroll
  for (int p = 0; p < 2; ++p) {
    int t = p * 32 + (tid >> 3), dc = tid & 7;
    s16x8 v = *(const s16x8*)&qkv[(size_t)(b * 2048 + t0 + t) * 3072 + 2048 + h * 64 + dc * 8];
#pragma unroll
    for (int j = 0; j < 8; ++j) TL[dc * 8 + j][t] = (unsigned short)v[j];
  }
  __syncthreads();
#pragma unroll
  for (int p = 0; p < 2; ++p) {
    int d = p * 32 + (tid >> 3), tc = tid & 7;
    s16x8 o = *(const s16x8*)&TL[d][tc * 8];
    *(s16x8*)&Vt[((size_t)((b * 16 + h) * 64 + d)) * 2048 + t0 + tc * 8] = o;
  }
}

// ---------------- kernel 5: attention ------------------------------------
// Per block: (qb, h, b). QBLK=64, KVBLK=64, 4 waves; wave w owns q rows [w*16, w*16+16).
__global__ __launch_bounds__(256, 2) void attn_kernel(
    const unsigned short* __restrict__ qkv, const unsigned short* __restrict__ Vt,
    float* __restrict__ out) {
  __shared__ __align__(16) unsigned short Qs[64][72];
  __shared__ __align__(16) unsigned short Ks[64][72];
  __shared__ __align__(16) unsigned short Vs[64][72];   // [d][s]
  __shared__ __align__(16) unsigned short Ps[4][16][72];
  const int tid = threadIdx.x, lane = tid & 63, wid = tid >> 6;
  const int g = lane >> 4, lm = lane & 15;
  const int qb = blockIdx.x, h = blockIdx.y, b = blockIdx.z;
  const int t0 = qb * 64;

  // stage Q tile [64][64]
  {
    const int r = tid >> 3, dc = tid & 7;
#pragma unroll
    for (int p = 0; p < 2; ++p) {
      s16x8 v = *(const s16x8*)&qkv[(size_t)(b * 2048 + t0 + p * 32 + r) * 3072 + h * 64 + dc * 8];
      *(s16x8*)&Qs[p * 32 + r][dc * 8] = v;
    }
  }
  __syncthreads();
  s16x8 qf[2];
#pragma unroll
  for (int hd = 0; hd < 2; ++hd)
    qf[hd] = *(const s16x8*)&Qs[wid * 16 + lm][hd * 32 + g * 8];

  f32x4 yacc[4] = {};
  const int nst = qb + 1;
  const size_t kbase = (size_t)(b * 2048) * 3072 + 1024 + h * 64;
  const size_t vbase = (size_t)((b * 16 + h) * 64) * 2048;

  for (int st = 0; st < nst; ++st) {
    const int s0 = st * 64;
    __syncthreads();  // previous iteration's reads of Ks/Vs done
    {
      const int r = tid >> 3, dc = tid & 7;
#pragma unroll
      for (int p = 0; p < 2; ++p) {
        const int rr = p * 32 + r;
        s16x8 kv = *(const s16x8*)&qkv[kbase + (size_t)(s0 + rr) * 3072 + dc * 8];
        *(s16x8*)&Ks[rr][dc * 8] = kv;
        s16x8 vv = *(const s16x8*)&Vt[vbase + (size_t)rr * 2048 + s0 + dc * 8];
        *(s16x8*)&Vs[rr][dc * 8] = vv;
      }
    }
    __syncthreads();  // staging visible

    const bool diag = (st == qb);
#pragma unroll
    for (int sb = 0; sb < 4; ++sb) {
      s16x8 bk0 = *(const s16x8*)&Ks[sb * 16 + lm][g * 8];
      s16x8 bk1 = *(const s16x8*)&Ks[sb * 16 + lm][32 + g * 8];
      f32x4 z = {};
      f32x4 s = MFMA_BF16(qf[1], bk1, z);
      s = MFMA_BF16(qf[0], bk0, s);
      // S frag: row q_local16 = g*4+r, col s_local16 = lm
#pragma unroll
      for (int r2 = 0; r2 < 4; ++r2) {
        float v = s[r2] * 0.125f;
        if (diag) {
          const int ql = wid * 16 + g * 4 + r2;     // local q within tile (t0 == s0)
          if (sb * 16 + lm > ql) v = 0.0f;
        }
        v = v > 0.0f ? v : 0.0f;                    // relu
        Ps[wid][g * 4 + r2][sb * 16 + lm] = f2bf(v);
      }
    }
    __syncthreads();  // Ps visible

    s16x8 pa0 = *(const s16x8*)&Ps[wid][lm][g * 8];
    s16x8 pa1 = *(const s16x8*)&Ps[wid][lm][32 + g * 8];
#pragma unroll
    for (int db = 0; db < 4; ++db) {
      s16x8 bv0 = *(const s16x8*)&Vs[db * 16 + lm][g * 8];
      s16x8 bv1 = *(const s16x8*)&Vs[db * 16 + lm][32 + g * 8];
      yacc[db] = MFMA_BF16(pa0, bv0, yacc[db]);
      yacc[db] = MFMA_BF16(pa1, bv1, yacc[db]);
    }
  }

  const size_t obase = (size_t)(b * 2048 + t0 + wid * 16) * 1024 + h * 64;
#pragma unroll
  for (int db = 0; db < 4; ++db)
#pragma unroll
    for (int r2 = 0; r2 < 4; ++r2)
      out[obase + (size_t)(g * 4 + r2) * 1024 + db * 16 + lm] = yacc[db][r2];
}

extern "C" void kernel_launch(void* const* d_in, const int* in_sizes, int n_in,
                              void* d_out, int out_size, void* d_ws, size_t ws_size,
                              hipStream_t stream) {
  const float* x    = (const float*)d_in[0];   // [2,2048,1024]
  const float* w    = (const float*)d_in[1];   // [1024,3072]
  const float* bias = (const float*)d_in[2];   // [3072]
  float* out = (float*)d_out;                  // [2,2048,1024] fp32

  // workspace layout (bf16 buffers); Vt aliases xb (xb dead after GEMM)
  unsigned short* xb  = (unsigned short*)d_ws;            // 4096*1024  (8 MB)
  unsigned short* wT  = xb + (size_t)4096 * 1024;         // 3072*1024  (6 MB)
  unsigned short* qkv = wT + (size_t)3072 * 1024;         // 4096*3072  (24 MB)
  unsigned short* Vt  = xb;                               // 2*16*64*2048 (8 MB), reuse

  cvt_x_kernel<<<4096, 256, 0, stream>>>(x, xb);
  transpose_w_kernel<<<dim3(48, 16), 256, 0, stream>>>(w, wT);
  gemm_qkv_kernel<<<dim3(24, 32), 256, 0, stream>>>(xb, wT, bias, qkv);
  transpose_v_kernel<<<dim3(32, 16, 2), 256, 0, stream>>>(qkv, Vt);
  attn_kernel<<<dim3(32, 16, 2), 256, 0, stream>>>(qkv, Vt, out);
}

// Round 2
// 98.092 us; speedup vs baseline: 1.2793x; 1.2793x over previous
//
#include <hip/hip_runtime.h>

// Problem: B=2, T=2048, C=1024, H=16, D=64
// qkv = x @ w + b ; q,k,v split; att = relu(causal(q k^T / 8)); y = att @ v
// Output fp32 [B,T,C]. Compute in bf16 MFMA with fp32 accum.

typedef unsigned int u32;
typedef float  f32x4 __attribute__((ext_vector_type(4)));
typedef short  s16x8 __attribute__((ext_vector_type(8)));

#define MFMA_BF16(a, b, c) __builtin_amdgcn_mfma_f32_16x16x32_bf16((a), (b), (c), 0, 0, 0)

#define GLOAD16(g, l)                                                        \
  __builtin_amdgcn_global_load_lds(                                          \
      (__attribute__((address_space(1))) void*)(g),                          \
      (__attribute__((address_space(3))) void*)(l), 16, 0, 0)

__device__ __forceinline__ unsigned short f2bf(float f) {
  union { float f; u32 u; } x; x.f = f;
  u32 r = (x.u + 0x7fffu + ((x.u >> 16) & 1u)) >> 16;
  return (unsigned short)r;
}

// ---------------- kernel 1: x fp32 -> bf16 ----------------
__global__ void cvt_x_kernel(const float* __restrict__ x, unsigned short* __restrict__ xb) {
  int i = blockIdx.x * 256 + threadIdx.x;
  float4 v = ((const float4*)x)[i];
  ushort4 o;
  o.x = f2bf(v.x); o.y = f2bf(v.y); o.z = f2bf(v.z); o.w = f2bf(v.w);
  ((ushort4*)xb)[i] = o;
}

// ---------------- kernel 2: w [1024][3072] fp32 -> wT [3072][1024] bf16 ----
__global__ void transpose_w_kernel(const float* __restrict__ w, unsigned short* __restrict__ wT) {
  __shared__ unsigned short TL[64][72];
  const int tid = threadIdx.x;
  const int c0 = blockIdx.x * 64;
  const int r0 = blockIdx.y * 64;
#pragma unroll
  for (int p = 0; p < 4; ++p) {
    int r = p * 16 + (tid >> 4);
    int c = (tid & 15) * 4;
    float4 v = *(const float4*)&w[(size_t)(r0 + r) * 3072 + c0 + c];
    TL[c + 0][r] = f2bf(v.x);
    TL[c + 1][r] = f2bf(v.y);
    TL[c + 2][r] = f2bf(v.z);
    TL[c + 3][r] = f2bf(v.w);
  }
  __syncthreads();
#pragma unroll
  for (int p = 0; p < 4; ++p) {
    int c = p * 16 + (tid >> 4);
    int r = (tid & 15) * 4;
    ushort4 o;
    o.x = TL[c][r + 0]; o.y = TL[c][r + 1]; o.z = TL[c][r + 2]; o.w = TL[c][r + 3];
    *(ushort4*)&wT[(size_t)(c0 + c) * 1024 + r0 + r] = o;
  }
}

// ---------------- kernel 3: GEMM qkv = xb @ wT^T + bias  (bf16 out) -------
__global__ __launch_bounds__(256, 2) void gemm_qkv_kernel(
    const unsigned short* __restrict__ A, const unsigned short* __restrict__ Bt,
    const float* __restrict__ bias, unsigned short* __restrict__ Cq) {
  __shared__ __align__(16) unsigned short As[128 * 32];
  __shared__ __align__(16) unsigned short Bs[128 * 32];
  const int tid = threadIdx.x;
  const int lane = tid & 63, wid = tid >> 6;
  const int wr = wid >> 1, wc = wid & 1;
  const int g = lane >> 4, lm = lane & 15;
  const int bm = blockIdx.y, bn = blockIdx.x;

  const unsigned short* gA = A  + (size_t)(bm * 128 + wid * 32 + (lane >> 2)) * 1024 + (lane & 3) * 8;
  const unsigned short* gB = Bt + (size_t)(bn * 128 + wid * 32 + (lane >> 2)) * 1024 + (lane & 3) * 8;
  unsigned short* lA0 = &As[wid * 1024];
  unsigned short* lA1 = &As[wid * 1024 + 512];
  unsigned short* lB0 = &Bs[wid * 1024];
  unsigned short* lB1 = &Bs[wid * 1024 + 512];

  f32x4 acc[4][4] = {};

  for (int kt = 0; kt < 32; ++kt) {
    __syncthreads();
    const unsigned short* a0 = gA + kt * 32;
    const unsigned short* b0 = gB + kt * 32;
    GLOAD16(a0,             lA0);
    GLOAD16(a0 + 16 * 1024, lA1);
    GLOAD16(b0,             lB0);
    GLOAD16(b0 + 16 * 1024, lB1);
    __syncthreads();

    s16x8 af[4], bf[4];
#pragma unroll
    for (int m = 0; m < 4; ++m)
      af[m] = *(const s16x8*)&As[(wr * 64 + m * 16 + lm) * 32 + g * 8];
#pragma unroll
    for (int n = 0; n < 4; ++n)
      bf[n] = *(const s16x8*)&Bs[(wc * 64 + n * 16 + lm) * 32 + g * 8];
#pragma unroll
    for (int m = 0; m < 4; ++m)
#pragma unroll
      for (int n = 0; n < 4; ++n)
        acc[m][n] = MFMA_BF16(af[m], bf[n], acc[m][n]);
  }

#pragma unroll
  for (int m = 0; m < 4; ++m) {
    const int row = bm * 128 + wr * 64 + m * 16 + g * 4;
#pragma unroll
    for (int n = 0; n < 4; ++n) {
      const int col = bn * 128 + wc * 64 + n * 16 + lm;
      const float bv = bias[col];
#pragma unroll
      for (int r = 0; r < 4; ++r)
        Cq[(size_t)(row + r) * 3072 + col] = f2bf(acc[m][n][r] + bv);
    }
  }
}

// ---------------- kernel 4: V part of qkv -> Vt [B][H][D][T] bf16 ---------
__global__ void transpose_v_kernel(const unsigned short* __restrict__ qkv,
                                   unsigned short* __restrict__ Vt) {
  __shared__ unsigned short TL[64][72];
  const int tid = threadIdx.x;
  const int t0 = blockIdx.x * 64;
  const int h = blockIdx.y;
  const int b = blockIdx.z;
#pragma unroll
  for (int p = 0; p < 2; ++p) {
    int t = p * 32 + (tid >> 3), dc = tid & 7;
    s16x8 v = *(const s16x8*)&qkv[(size_t)(b * 2048 + t0 + t) * 3072 + 2048 + h * 64 + dc * 8];
#pragma unroll
    for (int j = 0; j < 8; ++j) TL[dc * 8 + j][t] = (unsigned short)v[j];
  }
  __syncthreads();
#pragma unroll
  for (int p = 0; p < 2; ++p) {
    int d = p * 32 + (tid >> 3), tc = tid & 7;
    s16x8 o = *(const s16x8*)&TL[d][tc * 8];
    *(s16x8*)&Vt[((size_t)((b * 16 + h) * 64 + d)) * 2048 + t0 + tc * 8] = o;
  }
}

// ---------------- kernel 5: attention v2 ----------------------------------
// Block = paired q-tiles (31-j, j) of 64 rows -> uniform 33 KV-steps/block.
// 4 waves; wave owns 16 q rows. K/V double-buffered in LDS (swizzled),
// prefetched via regs (T14). Swapped QK^T (S^T=mfma(K,Q)) -> packed b64
// P-writes, wave-local P round trip (no barrier). One barrier per step.
__global__ __launch_bounds__(256, 2) void attn_kernel(
    const unsigned short* __restrict__ qkv, const unsigned short* __restrict__ Vt,
    float* __restrict__ out) {
  __shared__ __align__(16) unsigned short Ks[2][64 * 64];
  __shared__ __align__(16) unsigned short Vs[2][64 * 64];
  __shared__ __align__(16) unsigned short Ps[4][16 * 64];
  const int tid = threadIdx.x, lane = tid & 63, wid = tid >> 6;
  const int g = lane >> 4, lm = lane & 15;
  const int h = blockIdx.y, b = blockIdx.z;
  const size_t qbase = (size_t)(b * 2048) * 3072 + h * 64;
  const size_t kbase = qbase + 1024;
  const size_t vbase = (size_t)((b * 16 + h) * 64) * 2048;

  // staging geometry: 256 thr, thread covers row sr, elems [sc, sc+16)
  const int sr = tid >> 2;
  const int sc = (tid & 3) * 16;
  const int swz = (sr & 7) << 3;
  const unsigned lw0 = sr * 64 + ((sc + 0) ^ swz);
  const unsigned lw1 = sr * 64 + ((sc + 8) ^ swz);

  const int msk = (lm & 7) << 3;              // read-side swizzle (row = *16+lm)
  unsigned short* Pw = &Ps[wid][0];

  for (int ph = 0; ph < 2; ++ph) {
    const int qb = ph ? (int)blockIdx.x : 31 - (int)blockIdx.x;
    const int nst = qb + 1;
    const int qrow = qb * 64 + wid * 16;

    s16x8 qf0 = *(const s16x8*)&qkv[qbase + (size_t)(qrow + lm) * 3072 + g * 8];
    s16x8 qf1 = *(const s16x8*)&qkv[qbase + (size_t)(qrow + lm) * 3072 + 32 + g * 8];
    f32x4 yacc[4] = {};

    // stage step 0
    s16x8 kr0 = *(const s16x8*)&qkv[kbase + (size_t)sr * 3072 + sc];
    s16x8 kr1 = *(const s16x8*)&qkv[kbase + (size_t)sr * 3072 + sc + 8];
    s16x8 vr0 = *(const s16x8*)&Vt[vbase + (size_t)sr * 2048 + sc];
    s16x8 vr1 = *(const s16x8*)&Vt[vbase + (size_t)sr * 2048 + sc + 8];
    __syncthreads();                          // prev phase LDS reads done
    *(s16x8*)&Ks[0][lw0] = kr0; *(s16x8*)&Ks[0][lw1] = kr1;
    *(s16x8*)&Vs[0][lw0] = vr0; *(s16x8*)&Vs[0][lw1] = vr1;
    __syncthreads();

    int cur = 0;
    for (int st = 0; st < nst; ++st) {
      const int s0 = st * 64;
      const bool pf = (st + 1 < nst);
      if (pf) {                               // T14: issue next-tile loads early
        const size_t krow = kbase + (size_t)(s0 + 64 + sr) * 3072;
        kr0 = *(const s16x8*)&qkv[krow + sc];
        kr1 = *(const s16x8*)&qkv[krow + sc + 8];
        const size_t vrow = vbase + (size_t)sr * 2048 + s0 + 64;
        vr0 = *(const s16x8*)&Vt[vrow + sc];
        vr1 = *(const s16x8*)&Vt[vrow + sc + 8];
      }
      const unsigned short* Kc = &Ks[cur][0];
      const unsigned short* Vc = &Vs[cur][0];
      const bool diag = (st == qb);
#pragma unroll
      for (int sb = 0; sb < 4; ++sb) {
        s16x8 kf0 = *(const s16x8*)&Kc[(sb * 16 + lm) * 64 + ((g * 8) ^ msk)];
        s16x8 kf1 = *(const s16x8*)&Kc[(sb * 16 + lm) * 64 + ((32 + g * 8) ^ msk)];
        f32x4 z = {};
        f32x4 sacc = MFMA_BF16(kf1, qf1, z);       // S^T: rows=s, cols=q
        sacc = MFMA_BF16(kf0, qf0, sacc);
        const int sg = s0 + sb * 16 + g * 4;       // this lane's s base (global)
        const int qg = qrow + lm;
        ushort4 p4;
#pragma unroll
        for (int r2 = 0; r2 < 4; ++r2) {
          float v = sacc[r2] * 0.125f;
          v = v > 0.0f ? v : 0.0f;
          if (diag && (sg + r2 > qg)) v = 0.0f;
          ((unsigned short*)&p4)[r2] = f2bf(v);
        }
        *(ushort4*)&Pw[lm * 64 + ((sb * 16 + g * 4) ^ msk)] = p4;
      }
      asm volatile("" ::: "memory");               // keep P reads after writes
      s16x8 pa0 = *(const s16x8*)&Pw[lm * 64 + ((g * 8) ^ msk)];
      s16x8 pa1 = *(const s16x8*)&Pw[lm * 64 + ((32 + g * 8) ^ msk)];
#pragma unroll
      for (int db = 0; db < 4; ++db) {
        s16x8 vf0 = *(const s16x8*)&Vc[(db * 16 + lm) * 64 + ((g * 8) ^ msk)];
        s16x8 vf1 = *(const s16x8*)&Vc[(db * 16 + lm) * 64 + ((32 + g * 8) ^ msk)];
        yacc[db] = MFMA_BF16(pa0, vf0, yacc[db]);
        yacc[db] = MFMA_BF16(pa1, vf1, yacc[db]);
      }
      if (pf) {                               // write prefetched tile to other buf
        *(s16x8*)&Ks[cur ^ 1][lw0] = kr0; *(s16x8*)&Ks[cur ^ 1][lw1] = kr1;
        *(s16x8*)&Vs[cur ^ 1][lw0] = vr0; *(s16x8*)&Vs[cur ^ 1][lw1] = vr1;
      }
      __syncthreads();                        // single barrier per step
      cur ^= 1;
    }

    const size_t obase = (size_t)(b * 2048 + qrow) * 1024 + h * 64;
#pragma unroll
    for (int db = 0; db < 4; ++db)
#pragma unroll
      for (int r2 = 0; r2 < 4; ++r2)
        out[obase + (size_t)(g * 4 + r2) * 1024 + db * 16 + lm] = yacc[db][r2];
  }
}

extern "C" void kernel_launch(void* const* d_in, const int* in_sizes, int n_in,
                              void* d_out, int out_size, void* d_ws, size_t ws_size,
                              hipStream_t stream) {
  const float* x    = (const float*)d_in[0];
  const float* w    = (const float*)d_in[1];
  const float* bias = (const float*)d_in[2];
  float* out = (float*)d_out;

  unsigned short* xb  = (unsigned short*)d_ws;            // 4096*1024
  unsigned short* wT  = xb + (size_t)4096 * 1024;         // 3072*1024
  unsigned short* qkv = wT + (size_t)3072 * 1024;         // 4096*3072
  unsigned short* Vt  = xb;                               // reuse (xb dead after GEMM)

  cvt_x_kernel<<<4096, 256, 0, stream>>>(x, xb);
  transpose_w_kernel<<<dim3(48, 16), 256, 0, stream>>>(w, wT);
  gemm_qkv_kernel<<<dim3(24, 32), 256, 0, stream>>>(xb, wT, bias, qkv);
  transpose_v_kernel<<<dim3(32, 16, 2), 256, 0, stream>>>(qkv, Vt);
  attn_kernel<<<dim3(16, 16, 2), 256, 0, stream>>>(qkv, Vt, out);
}